// Round 1
// baseline (450.321 us; speedup 1.0000x reference)
//
#include <hip/hip_runtime.h>
#include <hip/hip_bf16.h>
#include <cstdint>
#include <cstddef>

typedef __bf16 bf8_t __attribute__((ext_vector_type(8)));
typedef __bf16 bf4_t __attribute__((ext_vector_type(4)));
typedef float  f4_t  __attribute__((ext_vector_type(4)));

#define CC 768
#define NROWS 32768           // 8*4096
#define NTOT 25165824         // 32768*768

__device__ __forceinline__ void gld16(const void* g, void* l) {
  __builtin_amdgcn_global_load_lds(
      (const __attribute__((address_space(1))) void*)g,
      (__attribute__((address_space(3))) void*)l, 16, 0, 0);
}

// ---------------- prep kernels ----------------

__global__ void make_cas(__bf16* __restrict__ cas) {
  int idx = blockIdx.x * 256 + threadIdx.x;      // 589824 total
  int i = idx / CC, j = idx - i * CC;
  int ij = (i * j) % CC;                          // exact arg reduction
  float ang = 6.283185307179586f * (float)ij / (float)CC;
  cas[idx] = (__bf16)(__cosf(ang) + __sinf(ang));
}

__global__ void cvt4(const float* __restrict__ x, __bf16* __restrict__ o) {
  int i = (blockIdx.x * 256 + threadIdx.x) * 4;
  float4 v = *(const float4*)(x + i);
  bf4_t r;
  r[0] = (__bf16)v.x; r[1] = (__bf16)v.y; r[2] = (__bf16)v.z; r[3] = (__bf16)v.w;
  *(bf4_t*)(o + i) = r;
}

// pack weights into MFMA B-fragment order: frag[(kt*12+nt)*64 + lane][j]
// B-frag semantics: lane holds B[k = kt*32 + (lane>>4)*8 + j][n = nt*16 + (lane&15)]
__global__ void pack_w1(const float* __restrict__ w1, __bf16* __restrict__ w1f) {
  int f = blockIdx.x * 256 + threadIdx.x;        // < 8*36*64*8 = 147456
  int j = f & 7, lane = (f >> 3) & 63, rest = f >> 9;
  int nt = rest % 12, kt = (rest / 12) % 3, blk = rest / 36;
  int k = kt * 32 + (lane >> 4) * 8 + j;          // 0..95  (input)
  int o = nt * 16 + (lane & 15);                  // 0..191 (output: [real|imag])
  float v = (o < 96) ? w1[(0 * 8 + blk) * 9216 + k * 96 + o]
                     : w1[(1 * 8 + blk) * 9216 + k * 96 + (o - 96)];
  w1f[f] = (__bf16)v;
}

__global__ void pack_w2(const float* __restrict__ w2, __bf16* __restrict__ w2f) {
  int f = blockIdx.x * 256 + threadIdx.x;        // < 8*72*64*8 = 294912
  int j = f & 7, lane = (f >> 3) & 63, rest = f >> 9;
  int nt = rest % 12, kt = (rest / 12) % 6, blk = rest / 72;
  int i = kt * 32 + (lane >> 4) * 8 + j;          // 0..191 (hidden: [ar|ai])
  int o = nt * 16 + (lane & 15);                  // 0..191 (out: [yr|yi])
  float v;
  if (o < 96) v = (i < 96) ?  w2[(0 * 8 + blk) * 9216 + i * 96 + o]
                           : -w2[(1 * 8 + blk) * 9216 + (i - 96) * 96 + o];
  else        v = (i < 96) ?  w2[(1 * 8 + blk) * 9216 + i * 96 + (o - 96)]
                           :  w2[(0 * 8 + blk) * 9216 + (i - 96) * 96 + (o - 96)];
  w2f[f] = (__bf16)v;
}

// ---------------- back GEMM (unchanged m97 structure; CAS symmetric => BT = CAS) --------
// mode 1: Cf[row,col] = acc*scale + Xres[row,col]
__global__ __launch_bounds__(256) void gemm_cas(
    const __bf16* __restrict__ A, const __bf16* __restrict__ BT,
    __bf16* __restrict__ Cb, float* __restrict__ Cf,
    const float* __restrict__ Xres, float scale, int mode)
{
  __shared__ __align__(16) __bf16 sA[128 * 32];
  __shared__ __align__(16) __bf16 sB[128 * 32];
  const int t = threadIdx.x;
  const int lane = t & 63, wid = t >> 6;
  const int wm = (wid >> 1) * 64, wn = (wid & 1) * 64;
  const int m0 = blockIdx.x * 128, n0 = blockIdx.y * 128;
  const int q = lane >> 4, r = lane & 15;
  const int srow = t >> 2, sseg = (t & 3) * 8;
  const __bf16* gA = A + (size_t)(m0 + srow) * CC + sseg;
  const __bf16* gB = BT + (size_t)(n0 + srow) * CC + sseg;
  __bf16* lA = sA + srow * 32 + sseg;
  __bf16* lB = sB + srow * 32 + sseg;

  f4_t acc[4][4] = {};
  for (int k0 = 0; k0 < CC; k0 += 32) {
    __syncthreads();
    gld16(gA + k0, lA);
    gld16(gA + (size_t)64 * CC + k0, lA + 64 * 32);
    gld16(gB + k0, lB);
    gld16(gB + (size_t)64 * CC + k0, lB + 64 * 32);
    __syncthreads();
    bf8_t af[4], bfr[4];
#pragma unroll
    for (int i = 0; i < 4; i++)
      af[i] = *(const bf8_t*)(sA + (wm + i * 16 + r) * 32 + q * 8);
#pragma unroll
    for (int j = 0; j < 4; j++)
      bfr[j] = *(const bf8_t*)(sB + (wn + j * 16 + r) * 32 + q * 8);
#pragma unroll
    for (int i = 0; i < 4; i++)
#pragma unroll
      for (int j = 0; j < 4; j++)
        acc[i][j] = __builtin_amdgcn_mfma_f32_16x16x32_bf16(af[i], bfr[j], acc[i][j], 0, 0, 0);
  }
  // D layout: col = lane&15, row = (lane>>4)*4 + reg
#pragma unroll
  for (int i = 0; i < 4; i++)
#pragma unroll
    for (int j = 0; j < 4; j++) {
      int col = n0 + wn + j * 16 + r;
#pragma unroll
      for (int rr = 0; rr < 4; rr++) {
        int row = m0 + wm + i * 16 + q * 4 + rr;
        size_t off = (size_t)row * CC + col;
        if (mode == 0) Cb[off] = (__bf16)acc[i][j][rr];
        else           Cf[off] = acc[i][j][rr] * scale + Xres[off];
      }
    }
}

// ---------------- fused V = X@CAS[:,blk] + block-diagonal MLP + softshrink ----------------
// Grid (256 row-tiles x 8 channel blocks), 384 threads = 6 waves.
// K-loop: BM=128, BN=96 (one channel block), m97 2-barrier structure, wave grid 2x3
// (64x32 per wave, acc[4][2]). Epilogue drops V into LDS vtile (stride 104 bf16 =
// 52 dwords: 20r mod 32 walks 8 banks -> ~2-4-way on the phase-1 ds_read_b128, vs
// 16-way at stride 96). Then the proven 6-wave mlp body runs on two 64-row half-passes
// reading vtile instead of global V. Eliminates the standalone mlp kernel and the
// 100 MB V round-trip.
__global__ __launch_bounds__(384, 3) void fused1(
    const __bf16* __restrict__ A, const __bf16* __restrict__ BT,
    const __bf16* __restrict__ w1f, const __bf16* __restrict__ w2f,
    const float* __restrict__ b1, const float* __restrict__ b2,
    __bf16* __restrict__ Z)
{
  // LDS plan (64 KB total -> 2 blocks/CU):
  //   [0,     14336): sA[128*32] (8 KB) + sB[96*32] (6 KB)   -- K-loop only
  //   [0,     25600): Hs[64*200]                             -- MLP (after K-loop)
  //   [26624, 53248): vtile[128*104]                         -- V tile, bf16
  //   [53248, 65536): zl[64*96]                              -- z staging for copyout
  __shared__ __align__(16) char smem[65536];
  __bf16* sA = (__bf16*)smem;
  __bf16* sB = (__bf16*)(smem + 8192);
  __bf16* Hs = (__bf16*)smem;
  __bf16* vt = (__bf16*)(smem + 26624);
  __bf16* zl = (__bf16*)(smem + 53248);

  const int t = threadIdx.x, lane = t & 63, w = t >> 6;   // w in 0..5
  const int blk = blockIdx.y;
  const int m0 = blockIdx.x * 128;
  const int n0 = blk * 96;
  const int q = lane >> 4, r = lane & 15;

  // ---- K-loop: V[128x96] = A[m0:m0+128,:] @ CAS[:, n0:n0+96] ----
  const int wm = w / 3, wn = w - 3 * wm;                  // 2x3 wave grid
  // staging: A = 512 x 16B units (u=t for all, u=384+t for waves 0,1); B = 384 units (u=t)
  const __bf16* gA  = A  + (size_t)(m0 + (t >> 2)) * CC + (t & 3) * 8;
  const __bf16* gA2 = A  + (size_t)(m0 + 96 + (t >> 2)) * CC + (t & 3) * 8;  // t<128 only
  const __bf16* gB  = BT + (size_t)(n0 + (t >> 2)) * CC + (t & 3) * 8;
  __bf16* lA  = sA + t * 8;
  __bf16* lA2 = sA + (384 + t) * 8;
  __bf16* lB  = sB + t * 8;

  f4_t acc[4][2] = {};
  for (int k0 = 0; k0 < CC; k0 += 32) {
    __syncthreads();
    gld16(gA + k0, lA);
    if (t < 128) gld16(gA2 + k0, lA2);     // wave-uniform (waves 0,1)
    gld16(gB + k0, lB);
    __syncthreads();
    bf8_t af[4], bfr[2];
#pragma unroll
    for (int i = 0; i < 4; i++)
      af[i] = *(const bf8_t*)(sA + (wm * 64 + i * 16 + r) * 32 + q * 8);
#pragma unroll
    for (int j = 0; j < 2; j++)
      bfr[j] = *(const bf8_t*)(sB + (wn * 32 + j * 16 + r) * 32 + q * 8);
#pragma unroll
    for (int i = 0; i < 4; i++)
#pragma unroll
      for (int j = 0; j < 2; j++)
        acc[i][j] = __builtin_amdgcn_mfma_f32_16x16x32_bf16(af[i], bfr[j], acc[i][j], 0, 0, 0);
  }
  // epilogue: V tile -> LDS (bf16), D layout col = lane&15, row = (lane>>4)*4 + reg
#pragma unroll
  for (int i = 0; i < 4; i++)
#pragma unroll
    for (int j = 0; j < 2; j++) {
      int col = wn * 32 + j * 16 + r;
#pragma unroll
      for (int rr = 0; rr < 4; rr++) {
        int row = wm * 64 + i * 16 + q * 4 + rr;
        vt[row * 104 + col] = (__bf16)acc[i][j][rr];
      }
    }

  // ---- load this wave's weight fragments into registers (once) ----
  const __bf16* w1b = w1f + (size_t)blk * (36 * 64 * 8);
  const __bf16* w2b = w2f + (size_t)blk * (72 * 64 * 8);
  bf8_t w1r[3][2], w2r[6][2];
#pragma unroll
  for (int kt = 0; kt < 3; kt++)
#pragma unroll
    for (int j = 0; j < 2; j++)
      w1r[kt][j] = *(const bf8_t*)(w1b + ((size_t)(kt * 12 + 2 * w + j) * 64 + lane) * 8);
#pragma unroll
  for (int kt = 0; kt < 6; kt++) {
    w2r[kt][0] = *(const bf8_t*)(w2b + ((size_t)(kt * 12 + w) * 64 + lane) * 8);
    w2r[kt][1] = *(const bf8_t*)(w2b + ((size_t)(kt * 12 + w + 6) * 64 + lane) * 8);
  }
  float bb[2];
#pragma unroll
  for (int j = 0; j < 2; j++) {
    int c = (2 * w + j) * 16 + r;
    bb[j] = (c < 96) ? b1[blk * 96 + c] : b1[768 + blk * 96 + (c - 96)];
  }
  const float br = b2[blk * 96 + w * 16 + r];
  const float bi = b2[768 + blk * 96 + w * 16 + r];

  for (int h = 0; h < 2; h++) {
    __syncthreads();   // h=0: vtile ready; h=1: Hs/zl safe to reuse
    // ---- phase 1: Hs[0:64][192] = relu(V W1 + b1), wave w writes cols [32w,32w+32) ----
#pragma unroll
    for (int rt = 0; rt < 4; rt++) {
      const __bf16* vp = vt + (h * 64 + rt * 16 + r) * 104 + q * 8;
      f4_t acc0 = {}, acc1 = {};
#pragma unroll
      for (int kt = 0; kt < 3; kt++) {
        bf8_t a = *(const bf8_t*)(vp + kt * 32);
        acc0 = __builtin_amdgcn_mfma_f32_16x16x32_bf16(a, w1r[kt][0], acc0, 0, 0, 0);
        acc1 = __builtin_amdgcn_mfma_f32_16x16x32_bf16(a, w1r[kt][1], acc1, 0, 0, 0);
      }
#pragma unroll
      for (int j = 0; j < 2; j++) {
        int c = (2 * w + j) * 16 + r;
        f4_t* ap = j ? &acc1 : &acc0;
#pragma unroll
        for (int rr = 0; rr < 4; rr++) {
          float v = (*ap)[rr] + bb[j];
          Hs[(rt * 16 + q * 4 + rr) * 200 + c] = (__bf16)(v > 0.f ? v : 0.f);
        }
      }
    }
    __syncthreads();
    // ---- phase 2: y = H W2pack + b2; z = ss(yr) - ss(yi); wave w -> z cols [16w,16w+16) ----
#pragma unroll
    for (int rt = 0; rt < 4; rt++) {
      f4_t ar = {}, ai = {};
#pragma unroll
      for (int kt = 0; kt < 6; kt++) {
        bf8_t a = *(const bf8_t*)(&Hs[(rt * 16 + r) * 200 + kt * 32 + q * 8]);
        ar = __builtin_amdgcn_mfma_f32_16x16x32_bf16(a, w2r[kt][0], ar, 0, 0, 0);
        ai = __builtin_amdgcn_mfma_f32_16x16x32_bf16(a, w2r[kt][1], ai, 0, 0, 0);
      }
#pragma unroll
      for (int rr = 0; rr < 4; rr++) {
        float yr = ar[rr] + br, yi = ai[rr] + bi;
        float sr = fabsf(yr) - 0.01f; sr = sr > 0.f ? copysignf(sr, yr) : 0.f;
        float si = fabsf(yi) - 0.01f; si = si > 0.f ? copysignf(si, yi) : 0.f;
        zl[(rt * 16 + q * 4 + rr) * 96 + w * 16 + r] = (__bf16)(sr - si);
      }
    }
    __syncthreads();
    // ---- copy-out: 64 rows x 48 dwords, coalesced ----
    {
      const uint32_t* zsrc = (const uint32_t*)zl;
      int cdw = t % 48, crow = t / 48;            // 8 rows per pass
      int rbase = m0 + h * 64;
#pragma unroll
      for (int it = 0; it < 8; it++) {
        int row = it * 8 + crow;
        uint32_t* dst = (uint32_t*)(Z + (size_t)(rbase + row) * CC + blk * 96);
        dst[cdw] = zsrc[row * 48 + cdw];
      }
    }
  }
}

// ---------------- launch ----------------

extern "C" void kernel_launch(void* const* d_in, const int* in_sizes, int n_in,
                              void* d_out, int out_size, void* d_ws, size_t ws_size,
                              hipStream_t stream) {
  const float* x  = (const float*)d_in[0];
  const float* w1 = (const float*)d_in[1];
  const float* b1 = (const float*)d_in[2];
  const float* w2 = (const float*)d_in[3];
  const float* b2 = (const float*)d_in[4];
  float* out = (float*)d_out;

  char* ws = (char*)d_ws;
  size_t off = 0;
  auto alloc = [&](size_t bytes) {
    char* p = ws + off;
    off += (bytes + 255) & ~(size_t)255;
    return p;
  };
  __bf16* casb = (__bf16*)alloc((size_t)CC * CC * 2);        // 1.18 MB
  __bf16* w1f  = (__bf16*)alloc((size_t)8 * 36 * 64 * 8 * 2);
  __bf16* w2f  = (__bf16*)alloc((size_t)8 * 72 * 64 * 8 * 2);
  __bf16* xb   = (__bf16*)alloc((size_t)NTOT * 2);           // 50.3 MB
  __bf16* vv   = (__bf16*)alloc((size_t)NTOT * 2);           // 50.3 MB (Z)

  make_cas<<<2304, 256, 0, stream>>>(casb);
  cvt4<<<24576, 256, 0, stream>>>(x, xb);
  pack_w1<<<576, 256, 0, stream>>>(w1, w1f);
  pack_w2<<<1152, 256, 0, stream>>>(w2, w2f);

  // Z = softshrink-MLP(Xbf16 @ CAS), fused per (row-tile, channel-block)
  fused1<<<dim3(256, 8), 384, 0, stream>>>(xb, casb, w1f, w2f, b1, b2, vv);
  // OUT = Z @ CAS / n_tot + X
  gemm_cas<<<dim3(256, 6), 256, 0, stream>>>(vv, casb, nullptr, out, x, 1.0f / 25165824.0f, 1);
}

// Round 2
// 428.607 us; speedup vs baseline: 1.0507x; 1.0507x over previous
//
#include <hip/hip_runtime.h>
#include <hip/hip_bf16.h>
#include <cstdint>
#include <cstddef>

typedef __bf16 bf8_t __attribute__((ext_vector_type(8)));
typedef __bf16 bf4_t __attribute__((ext_vector_type(4)));
typedef float  f4_t  __attribute__((ext_vector_type(4)));

#define CC 768
#define NROWS 32768           // 8*4096
#define NTOT 25165824         // 32768*768

__device__ __forceinline__ void gld16(const void* g, void* l) {
  __builtin_amdgcn_global_load_lds(
      (const __attribute__((address_space(1))) void*)g,
      (__attribute__((address_space(3))) void*)l, 16, 0, 0);
}

// ---------------- prep kernels ----------------

__global__ void make_cas(__bf16* __restrict__ cas) {
  int idx = blockIdx.x * 256 + threadIdx.x;      // 589824 total
  int i = idx / CC, j = idx - i * CC;
  int ij = (i * j) % CC;                          // exact arg reduction
  float ang = 6.283185307179586f * (float)ij / (float)CC;
  cas[idx] = (__bf16)(__cosf(ang) + __sinf(ang));
}

__global__ void cvt4(const float* __restrict__ x, __bf16* __restrict__ o) {
  int i = (blockIdx.x * 256 + threadIdx.x) * 4;
  float4 v = *(const float4*)(x + i);
  bf4_t r;
  r[0] = (__bf16)v.x; r[1] = (__bf16)v.y; r[2] = (__bf16)v.z; r[3] = (__bf16)v.w;
  *(bf4_t*)(o + i) = r;
}

// pack weights into MFMA B-fragment order: frag[(kt*12+nt)*64 + lane][j]
// B-frag semantics: lane holds B[k = kt*32 + (lane>>4)*8 + j][n = nt*16 + (lane&15)]
__global__ void pack_w1(const float* __restrict__ w1, __bf16* __restrict__ w1f) {
  int f = blockIdx.x * 256 + threadIdx.x;        // < 8*36*64*8 = 147456
  int j = f & 7, lane = (f >> 3) & 63, rest = f >> 9;
  int nt = rest % 12, kt = (rest / 12) % 3, blk = rest / 36;
  int k = kt * 32 + (lane >> 4) * 8 + j;          // 0..95  (input)
  int o = nt * 16 + (lane & 15);                  // 0..191 (output: [real|imag])
  float v = (o < 96) ? w1[(0 * 8 + blk) * 9216 + k * 96 + o]
                     : w1[(1 * 8 + blk) * 9216 + k * 96 + (o - 96)];
  w1f[f] = (__bf16)v;
}

__global__ void pack_w2(const float* __restrict__ w2, __bf16* __restrict__ w2f) {
  int f = blockIdx.x * 256 + threadIdx.x;        // < 8*72*64*8 = 294912
  int j = f & 7, lane = (f >> 3) & 63, rest = f >> 9;
  int nt = rest % 12, kt = (rest / 12) % 6, blk = rest / 72;
  int i = kt * 32 + (lane >> 4) * 8 + j;          // 0..191 (hidden: [ar|ai])
  int o = nt * 16 + (lane & 15);                  // 0..191 (out: [yr|yi])
  float v;
  if (o < 96) v = (i < 96) ?  w2[(0 * 8 + blk) * 9216 + i * 96 + o]
                           : -w2[(1 * 8 + blk) * 9216 + (i - 96) * 96 + o];
  else        v = (i < 96) ?  w2[(1 * 8 + blk) * 9216 + i * 96 + (o - 96)]
                           :  w2[(0 * 8 + blk) * 9216 + (i - 96) * 96 + (o - 96)];
  w2f[f] = (__bf16)v;
}

// ---------------- back GEMM (unchanged m97 structure; CAS symmetric => BT = CAS) --------
// mode 1: Cf[row,col] = acc*scale + Xres[row,col]
__global__ __launch_bounds__(256) void gemm_cas(
    const __bf16* __restrict__ A, const __bf16* __restrict__ BT,
    __bf16* __restrict__ Cb, float* __restrict__ Cf,
    const float* __restrict__ Xres, float scale, int mode)
{
  __shared__ __align__(16) __bf16 sA[128 * 32];
  __shared__ __align__(16) __bf16 sB[128 * 32];
  const int t = threadIdx.x;
  const int lane = t & 63, wid = t >> 6;
  const int wm = (wid >> 1) * 64, wn = (wid & 1) * 64;
  const int m0 = blockIdx.x * 128, n0 = blockIdx.y * 128;
  const int q = lane >> 4, r = lane & 15;
  const int srow = t >> 2, sseg = (t & 3) * 8;
  const __bf16* gA = A + (size_t)(m0 + srow) * CC + sseg;
  const __bf16* gB = BT + (size_t)(n0 + srow) * CC + sseg;
  __bf16* lA = sA + srow * 32 + sseg;
  __bf16* lB = sB + srow * 32 + sseg;

  f4_t acc[4][4] = {};
  for (int k0 = 0; k0 < CC; k0 += 32) {
    __syncthreads();
    gld16(gA + k0, lA);
    gld16(gA + (size_t)64 * CC + k0, lA + 64 * 32);
    gld16(gB + k0, lB);
    gld16(gB + (size_t)64 * CC + k0, lB + 64 * 32);
    __syncthreads();
    bf8_t af[4], bfr[4];
#pragma unroll
    for (int i = 0; i < 4; i++)
      af[i] = *(const bf8_t*)(sA + (wm + i * 16 + r) * 32 + q * 8);
#pragma unroll
    for (int j = 0; j < 4; j++)
      bfr[j] = *(const bf8_t*)(sB + (wn + j * 16 + r) * 32 + q * 8);
#pragma unroll
    for (int i = 0; i < 4; i++)
#pragma unroll
      for (int j = 0; j < 4; j++)
        acc[i][j] = __builtin_amdgcn_mfma_f32_16x16x32_bf16(af[i], bfr[j], acc[i][j], 0, 0, 0);
  }
  // D layout: col = lane&15, row = (lane>>4)*4 + reg
#pragma unroll
  for (int i = 0; i < 4; i++)
#pragma unroll
    for (int j = 0; j < 4; j++) {
      int col = n0 + wn + j * 16 + r;
#pragma unroll
      for (int rr = 0; rr < 4; rr++) {
        int row = m0 + wm + i * 16 + q * 4 + rr;
        size_t off = (size_t)row * CC + col;
        if (mode == 0) Cb[off] = (__bf16)acc[i][j][rr];
        else           Cf[off] = acc[i][j][rr] * scale + Xres[off];
      }
    }
}

// ---------------- fused V = X@CAS (BN=192) + 2x block-diagonal MLP + softshrink ----------
// Grid 1024 blocks (XCD-swizzled): sid -> (rowTile, cbp); BM=128, BN=192 (two channel
// blocks). 384 threads = 6 waves, wave grid 1M x 6N: each wave owns 128 rows x 32 cols,
// acc[8][2] = 16 MFMA/K-step (m97 parity; round-1's BN=96 had only 8 -> half density).
// A logical re-reads halve (4 passes vs 8). After the K-loop, two 64-row half-passes:
// write vtile half from acc, then run the proven 6-wave MLP body once per channel block
// (cb=0,1), weights reloaded per (h,cb) from L2-resident packed buffers.
// LDS 63.5 KB: [0,25600) Hs (aliases sA[0,8192)+sB[8192,20480) staging),
//              [25600,51200) vtile 64x200, [51200,63488) zl 64x96.
__global__ __launch_bounds__(384, 3) void fused2(
    const __bf16* __restrict__ A, const __bf16* __restrict__ BT,
    const __bf16* __restrict__ w1f, const __bf16* __restrict__ w2f,
    const float* __restrict__ b1, const float* __restrict__ b2,
    __bf16* __restrict__ Z)
{
  __shared__ __align__(16) char smem[63488];
  __bf16* sA = (__bf16*)smem;
  __bf16* sB = (__bf16*)(smem + 8192);
  __bf16* Hs = (__bf16*)smem;
  __bf16* vt = (__bf16*)(smem + 25600);
  __bf16* zl = (__bf16*)(smem + 51200);

  const int t = threadIdx.x, lane = t & 63, w = t >> 6;   // w in 0..5
  // bijective XCD swizzle (nwg=1024 % 8 == 0): each XCD gets 128 consecutive sids
  // = 32 row-tiles x 4 cb-pairs, x-fastest -> same row-tile's 4 cbp adjacent in time.
  const int id = blockIdx.x;
  const int sid = (id & 7) * 128 + (id >> 3);
  const int cbp = sid & 3;                 // channel-block pair 0..3
  const int m0 = (sid >> 2) * 128;         // row tile
  const int n0 = cbp * 192;
  const int q = lane >> 4, r = lane & 15;

  // ---- K-loop: V[128x192] = A[m0:m0+128,:] @ CAS[:, n0:n0+192] ----
  // staging per K-step: A 512x16B units (u=t, plus u=384+t for t<128), B 768 units
  // (u=t and u=384+t). gld16 dest = wave-uniform base + lane*16 (contiguous). ✓
  const __bf16* gA  = A  + (size_t)(m0 + (t >> 2)) * CC + (t & 3) * 8;
  const __bf16* gA2 = A  + (size_t)(m0 + 96 + (t >> 2)) * CC + (t & 3) * 8;   // t<128
  const __bf16* gB  = BT + (size_t)(n0 + (t >> 2)) * CC + (t & 3) * 8;
  const __bf16* gB2 = BT + (size_t)(n0 + 96 + (t >> 2)) * CC + (t & 3) * 8;
  __bf16* lA  = sA + t * 8;
  __bf16* lA2 = sA + (384 + t) * 8;
  __bf16* lB  = sB + t * 8;
  __bf16* lB2 = sB + (384 + t) * 8;

  f4_t acc[8][2] = {};
  for (int k0 = 0; k0 < CC; k0 += 32) {
    __syncthreads();
    gld16(gA + k0, lA);
    if (t < 128) gld16(gA2 + k0, lA2);     // wave-uniform (waves 0,1)
    gld16(gB + k0, lB);
    gld16(gB2 + k0, lB2);
    __syncthreads();
    bf8_t af[8], bfr[2];
#pragma unroll
    for (int i = 0; i < 8; i++)
      af[i] = *(const bf8_t*)(sA + (i * 16 + r) * 32 + q * 8);
#pragma unroll
    for (int j = 0; j < 2; j++)
      bfr[j] = *(const bf8_t*)(sB + (w * 32 + j * 16 + r) * 32 + q * 8);
#pragma unroll
    for (int i = 0; i < 8; i++)
#pragma unroll
      for (int j = 0; j < 2; j++)
        acc[i][j] = __builtin_amdgcn_mfma_f32_16x16x32_bf16(af[i], bfr[j], acc[i][j], 0, 0, 0);
  }

  // ---- two 64-row half-passes; all indices compile-time (h unrolled: acc[4h+ii]) ----
#pragma unroll
  for (int h = 0; h < 2; h++) {
    // write this half's V rows to vtile (D layout: col=lane&15 grp, row=(lane>>4)*4+rr)
#pragma unroll
    for (int ii = 0; ii < 4; ii++)
#pragma unroll
      for (int j = 0; j < 2; j++) {
        int col = w * 32 + j * 16 + r;
#pragma unroll
        for (int rr = 0; rr < 4; rr++) {
          int row = ii * 16 + q * 4 + rr;
          vt[row * 200 + col] = (__bf16)acc[h * 4 + ii][j][rr];
        }
      }
    __syncthreads();

#pragma unroll
    for (int cb = 0; cb < 2; cb++) {
      const int bidx = cbp * 2 + cb;
      // ---- this wave's weight fragments (L2-resident, 18 x 16B loads) ----
      const __bf16* w1b = w1f + (size_t)bidx * (36 * 64 * 8);
      const __bf16* w2b = w2f + (size_t)bidx * (72 * 64 * 8);
      bf8_t w1r[3][2], w2r[6][2];
#pragma unroll
      for (int kt = 0; kt < 3; kt++)
#pragma unroll
        for (int j = 0; j < 2; j++)
          w1r[kt][j] = *(const bf8_t*)(w1b + ((size_t)(kt * 12 + 2 * w + j) * 64 + lane) * 8);
#pragma unroll
      for (int kt = 0; kt < 6; kt++) {
        w2r[kt][0] = *(const bf8_t*)(w2b + ((size_t)(kt * 12 + w) * 64 + lane) * 8);
        w2r[kt][1] = *(const bf8_t*)(w2b + ((size_t)(kt * 12 + w + 6) * 64 + lane) * 8);
      }
      float bb[2];
#pragma unroll
      for (int j = 0; j < 2; j++) {
        int c = (2 * w + j) * 16 + r;
        bb[j] = (c < 96) ? b1[bidx * 96 + c] : b1[768 + bidx * 96 + (c - 96)];
      }
      const float br = b2[bidx * 96 + w * 16 + r];
      const float bi = b2[768 + bidx * 96 + w * 16 + r];

      // ---- phase 1: Hs[64][192] = relu(V[:,cb*96:+96] W1 + b1), wave w: cols [32w,32w+32)
#pragma unroll
      for (int rt = 0; rt < 4; rt++) {
        const __bf16* vp = vt + (rt * 16 + r) * 200 + cb * 96 + q * 8;
        f4_t a0 = {}, a1 = {};
#pragma unroll
        for (int kt = 0; kt < 3; kt++) {
          bf8_t a = *(const bf8_t*)(vp + kt * 32);
          a0 = __builtin_amdgcn_mfma_f32_16x16x32_bf16(a, w1r[kt][0], a0, 0, 0, 0);
          a1 = __builtin_amdgcn_mfma_f32_16x16x32_bf16(a, w1r[kt][1], a1, 0, 0, 0);
        }
#pragma unroll
        for (int j = 0; j < 2; j++) {
          int c = (2 * w + j) * 16 + r;
          f4_t* ap = j ? &a1 : &a0;
#pragma unroll
          for (int rr = 0; rr < 4; rr++) {
            float v = (*ap)[rr] + bb[j];
            Hs[(rt * 16 + q * 4 + rr) * 200 + c] = (__bf16)(v > 0.f ? v : 0.f);
          }
        }
      }
      __syncthreads();
      // ---- phase 2: y = H W2pack + b2; z = ss(yr)-ss(yi); wave w -> z cols [16w,16w+16)
#pragma unroll
      for (int rt = 0; rt < 4; rt++) {
        f4_t ar = {}, ai = {};
#pragma unroll
        for (int kt = 0; kt < 6; kt++) {
          bf8_t a = *(const bf8_t*)(&Hs[(rt * 16 + r) * 200 + kt * 32 + q * 8]);
          ar = __builtin_amdgcn_mfma_f32_16x16x32_bf16(a, w2r[kt][0], ar, 0, 0, 0);
          ai = __builtin_amdgcn_mfma_f32_16x16x32_bf16(a, w2r[kt][1], ai, 0, 0, 0);
        }
#pragma unroll
        for (int rr = 0; rr < 4; rr++) {
          float yr = ar[rr] + br, yi = ai[rr] + bi;
          float sr = fabsf(yr) - 0.01f; sr = sr > 0.f ? copysignf(sr, yr) : 0.f;
          float si = fabsf(yi) - 0.01f; si = si > 0.f ? copysignf(si, yi) : 0.f;
          zl[(rt * 16 + q * 4 + rr) * 96 + w * 16 + r] = (__bf16)(sr - si);
        }
      }
      __syncthreads();
      // ---- copy-out: 64 rows x 48 dwords, coalesced ----
      {
        const uint32_t* zsrc = (const uint32_t*)zl;
        int cdw = t % 48, crow = t / 48;          // 8 rows per pass
        int rbase = m0 + h * 64;
#pragma unroll
        for (int it = 0; it < 8; it++) {
          int row = it * 8 + crow;
          uint32_t* dst = (uint32_t*)(Z + (size_t)(rbase + row) * CC + n0 + cb * 96);
          dst[cdw] = zsrc[row * 48 + cdw];
        }
      }
      // no sync needed here: next write to Hs (cb=1 phase1) is ordered after the
      // phase2 sync; next write to zl is after cb=1's phase1->phase2 sync; next
      // write to vtile (h=1) is after cb=1 phase1's trailing sync.
    }
  }
}

// ---------------- launch ----------------

extern "C" void kernel_launch(void* const* d_in, const int* in_sizes, int n_in,
                              void* d_out, int out_size, void* d_ws, size_t ws_size,
                              hipStream_t stream) {
  const float* x  = (const float*)d_in[0];
  const float* w1 = (const float*)d_in[1];
  const float* b1 = (const float*)d_in[2];
  const float* w2 = (const float*)d_in[3];
  const float* b2 = (const float*)d_in[4];
  float* out = (float*)d_out;

  char* ws = (char*)d_ws;
  size_t off = 0;
  auto alloc = [&](size_t bytes) {
    char* p = ws + off;
    off += (bytes + 255) & ~(size_t)255;
    return p;
  };
  __bf16* casb = (__bf16*)alloc((size_t)CC * CC * 2);        // 1.18 MB
  __bf16* w1f  = (__bf16*)alloc((size_t)8 * 36 * 64 * 8 * 2);
  __bf16* w2f  = (__bf16*)alloc((size_t)8 * 72 * 64 * 8 * 2);
  __bf16* xb   = (__bf16*)alloc((size_t)NTOT * 2);           // 50.3 MB
  __bf16* vv   = (__bf16*)alloc((size_t)NTOT * 2);           // 50.3 MB (Z)

  make_cas<<<2304, 256, 0, stream>>>(casb);
  cvt4<<<24576, 256, 0, stream>>>(x, xb);
  pack_w1<<<576, 256, 0, stream>>>(w1, w1f);
  pack_w2<<<1152, 256, 0, stream>>>(w2, w2f);

  // Z = softshrink-MLP(Xbf16 @ CAS), fused per (row-tile, channel-block-pair)
  fused2<<<1024, 384, 0, stream>>>(xb, casb, w1f, w2f, b1, b2, vv);
  // OUT = Z @ CAS / n_tot + X
  gemm_cas<<<dim3(256, 6), 256, 0, stream>>>(vv, casb, nullptr, out, x, 1.0f / 25165824.0f, 1);
}

// Round 3
// 368.455 us; speedup vs baseline: 1.2222x; 1.1633x over previous
//
#include <hip/hip_runtime.h>
#include <hip/hip_bf16.h>
#include <cstdint>
#include <cstddef>

typedef __bf16 bf8_t __attribute__((ext_vector_type(8)));
typedef __bf16 bf4_t __attribute__((ext_vector_type(4)));
typedef float  f4_t  __attribute__((ext_vector_type(4)));

#define CC 768
#define NROWS 32768           // 8*4096
#define NTOT 25165824         // 32768*768

__device__ __forceinline__ void gld16(const void* g, void* l) {
  __builtin_amdgcn_global_load_lds(
      (const __attribute__((address_space(1))) void*)g,
      (__attribute__((address_space(3))) void*)l, 16, 0, 0);
}

// ---------------- prep kernels ----------------

__global__ void make_cas(__bf16* __restrict__ cas) {
  int idx = blockIdx.x * 256 + threadIdx.x;      // 589824 total
  int i = idx / CC, j = idx - i * CC;
  int ij = (i * j) % CC;                          // exact arg reduction
  float ang = 6.283185307179586f * (float)ij / (float)CC;
  cas[idx] = (__bf16)(__cosf(ang) + __sinf(ang));
}

__global__ void cvt4(const float* __restrict__ x, __bf16* __restrict__ o) {
  int i = (blockIdx.x * 256 + threadIdx.x) * 4;
  float4 v = *(const float4*)(x + i);
  bf4_t r;
  r[0] = (__bf16)v.x; r[1] = (__bf16)v.y; r[2] = (__bf16)v.z; r[3] = (__bf16)v.w;
  *(bf4_t*)(o + i) = r;
}

// pack weights into MFMA B-fragment order: frag[(kt*12+nt)*64 + lane][j]
// B-frag semantics: lane holds B[k = kt*32 + (lane>>4)*8 + j][n = nt*16 + (lane&15)]
__global__ void pack_w1(const float* __restrict__ w1, __bf16* __restrict__ w1f) {
  int f = blockIdx.x * 256 + threadIdx.x;        // < 8*36*64*8 = 147456
  int j = f & 7, lane = (f >> 3) & 63, rest = f >> 9;
  int nt = rest % 12, kt = (rest / 12) % 3, blk = rest / 36;
  int k = kt * 32 + (lane >> 4) * 8 + j;          // 0..95  (input)
  int o = nt * 16 + (lane & 15);                  // 0..191 (output: [real|imag])
  float v = (o < 96) ? w1[(0 * 8 + blk) * 9216 + k * 96 + o]
                     : w1[(1 * 8 + blk) * 9216 + k * 96 + (o - 96)];
  w1f[f] = (__bf16)v;
}

__global__ void pack_w2(const float* __restrict__ w2, __bf16* __restrict__ w2f) {
  int f = blockIdx.x * 256 + threadIdx.x;        // < 8*72*64*8 = 294912
  int j = f & 7, lane = (f >> 3) & 63, rest = f >> 9;
  int nt = rest % 12, kt = (rest / 12) % 6, blk = rest / 72;
  int i = kt * 32 + (lane >> 4) * 8 + j;          // 0..191 (hidden: [ar|ai])
  int o = nt * 16 + (lane & 15);                  // 0..191 (out: [yr|yi])
  float v;
  if (o < 96) v = (i < 96) ?  w2[(0 * 8 + blk) * 9216 + i * 96 + o]
                           : -w2[(1 * 8 + blk) * 9216 + (i - 96) * 96 + o];
  else        v = (i < 96) ?  w2[(1 * 8 + blk) * 9216 + i * 96 + (o - 96)]
                           :  w2[(0 * 8 + blk) * 9216 + (i - 96) * 96 + (o - 96)];
  w2f[f] = (__bf16)v;
}

// ---------------- back GEMM v2: counted-vmcnt 3-buffer pipeline + coalesced epilogue ----
// OUT[row,col] = (Z @ CAS)[row,col] * scale + Xres[row,col]   (f32 out)
// 128x128 tile, 4 waves. K-loop: 3 LDS buffers (16 KB each), stage tile t+2 BEFORE
// computing tile t, wait vmcnt(8) (= tiles t+1,t+2 in flight, 4 loads each) -- never
// drain to 0 in the loop (T3/T4). Tail stages clamp to tile 23 (duplicate, never read)
// to keep vmcnt arithmetic uniform. Epilogue: stage C f32 through LDS in two 64-row
// halves; copy-out does dwordx4 Xres-load + FMA + dwordx4 store, fully coalesced
// (vs 64 scattered 4B stores/thread in v1).
__global__ __launch_bounds__(256, 2) void gemm_back(
    const __bf16* __restrict__ Zb, const __bf16* __restrict__ BT,
    float* __restrict__ Cf, const float* __restrict__ Xres, float scale)
{
  __shared__ __align__(16) char smem[49152];     // 3 x (sA 8KB | sB 8KB)
  const int t = threadIdx.x;
  const int lane = t & 63, wid = t >> 6;
  const int wm = (wid >> 1) * 64, wn = (wid & 1) * 64;

  // bijective XCD-chunked swizzle (1536 % 8 == 0): 192 consecutive sids per XCD;
  // sid -> (m-tile = sid/6, n-tile = sid%6) so the 6 blocks sharing an A-panel are
  // adjacent within one XCD's L2.
  const int id = blockIdx.x;
  const int sid = (id & 7) * 192 + (id >> 3);
  const int m0 = (sid / 6) * 128, n0 = (sid % 6) * 128;

  const int q = lane >> 4, r = lane & 15;
  const __bf16* gA = Zb + (size_t)(m0 + (t >> 2)) * CC + (t & 3) * 8;
  const __bf16* gB = BT + (size_t)(n0 + (t >> 2)) * CC + (t & 3) * 8;
  const int ldsOff = (t >> 2) * 32 + (t & 3) * 8;  // byte off = t*16 (lane-linear) ✓

  auto stage = [&](int b, int tile) {
    int k0 = tile * 32;
    __bf16* lA = (__bf16*)(smem + b * 16384) + ldsOff;
    __bf16* lB = (__bf16*)(smem + b * 16384 + 8192) + ldsOff;
    gld16(gA + k0, lA);
    gld16(gA + (size_t)64 * CC + k0, lA + 64 * 32);
    gld16(gB + k0, lB);
    gld16(gB + (size_t)64 * CC + k0, lB + 64 * 32);
  };

  f4_t acc[4][4] = {};
  stage(0, 0);
  stage(1, 1);
  for (int tile = 0; tile < 24; ++tile) {
    int nt = tile + 2; if (nt > 23) nt = 23;       // clamped duplicate in tail
    stage((tile + 2) % 3, nt);
    asm volatile("s_waitcnt vmcnt(8)" ::: "memory");   // tile `tile` complete
    __builtin_amdgcn_s_barrier();
    const __bf16* sA = (const __bf16*)(smem + (tile % 3) * 16384);
    const __bf16* sB = sA + 8192 / 2;
    bf8_t af[4], bfr[4];
#pragma unroll
    for (int i = 0; i < 4; i++)
      af[i] = *(const bf8_t*)(sA + (wm + i * 16 + r) * 32 + q * 8);
#pragma unroll
    for (int j = 0; j < 4; j++)
      bfr[j] = *(const bf8_t*)(sB + (wn + j * 16 + r) * 32 + q * 8);
#pragma unroll
    for (int i = 0; i < 4; i++)
#pragma unroll
      for (int j = 0; j < 4; j++)
        acc[i][j] = __builtin_amdgcn_mfma_f32_16x16x32_bf16(af[i], bfr[j], acc[i][j], 0, 0, 0);
    __builtin_amdgcn_s_barrier();   // all waves done with buf[tile%3] before it's re-staged
  }

  // ---- epilogue: LDS-staged coalesced f32 writeback, two 64-row halves ----
  float* cs = (float*)smem;                        // 64 x 132 f32 = 33 KB < 48 KB
#pragma unroll
  for (int h = 0; h < 2; ++h) {
    __builtin_amdgcn_s_barrier();                  // prev half's copy-out done
    if ((wid >> 1) == h) {                         // waves owning rows [64h, 64h+64)
#pragma unroll
      for (int i = 0; i < 4; i++)
#pragma unroll
        for (int j = 0; j < 4; j++)
#pragma unroll
          for (int rr = 0; rr < 4; rr++)
            cs[(i * 16 + q * 4 + rr) * 132 + wn + j * 16 + r] = acc[i][j][rr];
    }
    __builtin_amdgcn_s_barrier();
    const int u = t & 31, row8 = t >> 5;           // 32 x 16B units per row, 8 rows/pass
#pragma unroll
    for (int p = 0; p < 8; ++p) {
      int rl = p * 8 + row8;
      size_t goff = (size_t)(m0 + h * 64 + rl) * CC + n0 + u * 4;
      f4_t xr = *(const f4_t*)(Xres + goff);
      f4_t cv = *(const f4_t*)(cs + rl * 132 + u * 4);
      f4_t o;
      o[0] = cv[0] * scale + xr[0];
      o[1] = cv[1] * scale + xr[1];
      o[2] = cv[2] * scale + xr[2];
      o[3] = cv[3] * scale + xr[3];
      *(f4_t*)(Cf + goff) = o;
    }
  }
}

// ---------------- fused V = X@CAS (BN=192) + 2x block-diagonal MLP + softshrink ----------
// (unchanged from round 2 — 142.6 us; pipeline port deferred until gemm_back validates)
__global__ __launch_bounds__(384, 3) void fused2(
    const __bf16* __restrict__ A, const __bf16* __restrict__ BT,
    const __bf16* __restrict__ w1f, const __bf16* __restrict__ w2f,
    const float* __restrict__ b1, const float* __restrict__ b2,
    __bf16* __restrict__ Z)
{
  __shared__ __align__(16) char smem[63488];
  __bf16* sA = (__bf16*)smem;
  __bf16* sB = (__bf16*)(smem + 8192);
  __bf16* Hs = (__bf16*)smem;
  __bf16* vt = (__bf16*)(smem + 25600);
  __bf16* zl = (__bf16*)(smem + 51200);

  const int t = threadIdx.x, lane = t & 63, w = t >> 6;   // w in 0..5
  const int id = blockIdx.x;
  const int sid = (id & 7) * 128 + (id >> 3);
  const int cbp = sid & 3;                 // channel-block pair 0..3
  const int m0 = (sid >> 2) * 128;         // row tile
  const int n0 = cbp * 192;
  const int q = lane >> 4, r = lane & 15;

  const __bf16* gA  = A  + (size_t)(m0 + (t >> 2)) * CC + (t & 3) * 8;
  const __bf16* gA2 = A  + (size_t)(m0 + 96 + (t >> 2)) * CC + (t & 3) * 8;   // t<128
  const __bf16* gB  = BT + (size_t)(n0 + (t >> 2)) * CC + (t & 3) * 8;
  const __bf16* gB2 = BT + (size_t)(n0 + 96 + (t >> 2)) * CC + (t & 3) * 8;
  __bf16* lA  = sA + t * 8;
  __bf16* lA2 = sA + (384 + t) * 8;
  __bf16* lB  = sB + t * 8;
  __bf16* lB2 = sB + (384 + t) * 8;

  f4_t acc[8][2] = {};
  for (int k0 = 0; k0 < CC; k0 += 32) {
    __syncthreads();
    gld16(gA + k0, lA);
    if (t < 128) gld16(gA2 + k0, lA2);     // wave-uniform (waves 0,1)
    gld16(gB + k0, lB);
    gld16(gB2 + k0, lB2);
    __syncthreads();
    bf8_t af[8], bfr[2];
#pragma unroll
    for (int i = 0; i < 8; i++)
      af[i] = *(const bf8_t*)(sA + (i * 16 + r) * 32 + q * 8);
#pragma unroll
    for (int j = 0; j < 2; j++)
      bfr[j] = *(const bf8_t*)(sB + (w * 32 + j * 16 + r) * 32 + q * 8);
#pragma unroll
    for (int i = 0; i < 8; i++)
#pragma unroll
      for (int j = 0; j < 2; j++)
        acc[i][j] = __builtin_amdgcn_mfma_f32_16x16x32_bf16(af[i], bfr[j], acc[i][j], 0, 0, 0);
  }

#pragma unroll
  for (int h = 0; h < 2; h++) {
#pragma unroll
    for (int ii = 0; ii < 4; ii++)
#pragma unroll
      for (int j = 0; j < 2; j++) {
        int col = w * 32 + j * 16 + r;
#pragma unroll
        for (int rr = 0; rr < 4; rr++) {
          int row = ii * 16 + q * 4 + rr;
          vt[row * 200 + col] = (__bf16)acc[h * 4 + ii][j][rr];
        }
      }
    __syncthreads();

#pragma unroll
    for (int cb = 0; cb < 2; cb++) {
      const int bidx = cbp * 2 + cb;
      const __bf16* w1b = w1f + (size_t)bidx * (36 * 64 * 8);
      const __bf16* w2b = w2f + (size_t)bidx * (72 * 64 * 8);
      bf8_t w1r[3][2], w2r[6][2];
#pragma unroll
      for (int kt = 0; kt < 3; kt++)
#pragma unroll
        for (int j = 0; j < 2; j++)
          w1r[kt][j] = *(const bf8_t*)(w1b + ((size_t)(kt * 12 + 2 * w + j) * 64 + lane) * 8);
#pragma unroll
      for (int kt = 0; kt < 6; kt++) {
        w2r[kt][0] = *(const bf8_t*)(w2b + ((size_t)(kt * 12 + w) * 64 + lane) * 8);
        w2r[kt][1] = *(const bf8_t*)(w2b + ((size_t)(kt * 12 + w + 6) * 64 + lane) * 8);
      }
      float bb[2];
#pragma unroll
      for (int j = 0; j < 2; j++) {
        int c = (2 * w + j) * 16 + r;
        bb[j] = (c < 96) ? b1[bidx * 96 + c] : b1[768 + bidx * 96 + (c - 96)];
      }
      const float br = b2[bidx * 96 + w * 16 + r];
      const float bi = b2[768 + bidx * 96 + w * 16 + r];

#pragma unroll
      for (int rt = 0; rt < 4; rt++) {
        const __bf16* vp = vt + (rt * 16 + r) * 200 + cb * 96 + q * 8;
        f4_t a0 = {}, a1 = {};
#pragma unroll
        for (int kt = 0; kt < 3; kt++) {
          bf8_t a = *(const bf8_t*)(vp + kt * 32);
          a0 = __builtin_amdgcn_mfma_f32_16x16x32_bf16(a, w1r[kt][0], a0, 0, 0, 0);
          a1 = __builtin_amdgcn_mfma_f32_16x16x32_bf16(a, w1r[kt][1], a1, 0, 0, 0);
        }
#pragma unroll
        for (int j = 0; j < 2; j++) {
          int c = (2 * w + j) * 16 + r;
          f4_t* ap = j ? &a1 : &a0;
#pragma unroll
          for (int rr = 0; rr < 4; rr++) {
            float v = (*ap)[rr] + bb[j];
            Hs[(rt * 16 + q * 4 + rr) * 200 + c] = (__bf16)(v > 0.f ? v : 0.f);
          }
        }
      }
      __syncthreads();
#pragma unroll
      for (int rt = 0; rt < 4; rt++) {
        f4_t ar = {}, ai = {};
#pragma unroll
        for (int kt = 0; kt < 6; kt++) {
          bf8_t a = *(const bf8_t*)(&Hs[(rt * 16 + r) * 200 + kt * 32 + q * 8]);
          ar = __builtin_amdgcn_mfma_f32_16x16x32_bf16(a, w2r[kt][0], ar, 0, 0, 0);
          ai = __builtin_amdgcn_mfma_f32_16x16x32_bf16(a, w2r[kt][1], ai, 0, 0, 0);
        }
#pragma unroll
        for (int rr = 0; rr < 4; rr++) {
          float yr = ar[rr] + br, yi = ai[rr] + bi;
          float sr = fabsf(yr) - 0.01f; sr = sr > 0.f ? copysignf(sr, yr) : 0.f;
          float si = fabsf(yi) - 0.01f; si = si > 0.f ? copysignf(si, yi) : 0.f;
          zl[(rt * 16 + q * 4 + rr) * 96 + w * 16 + r] = (__bf16)(sr - si);
        }
      }
      __syncthreads();
      {
        const uint32_t* zsrc = (const uint32_t*)zl;
        int cdw = t % 48, crow = t / 48;
        int rbase = m0 + h * 64;
#pragma unroll
        for (int it = 0; it < 8; it++) {
          int row = it * 8 + crow;
          uint32_t* dst = (uint32_t*)(Z + (size_t)(rbase + row) * CC + n0 + cb * 96);
          dst[cdw] = zsrc[row * 48 + cdw];
        }
      }
    }
  }
}

// ---------------- launch ----------------

extern "C" void kernel_launch(void* const* d_in, const int* in_sizes, int n_in,
                              void* d_out, int out_size, void* d_ws, size_t ws_size,
                              hipStream_t stream) {
  const float* x  = (const float*)d_in[0];
  const float* w1 = (const float*)d_in[1];
  const float* b1 = (const float*)d_in[2];
  const float* w2 = (const float*)d_in[3];
  const float* b2 = (const float*)d_in[4];
  float* out = (float*)d_out;

  char* ws = (char*)d_ws;
  size_t off = 0;
  auto alloc = [&](size_t bytes) {
    char* p = ws + off;
    off += (bytes + 255) & ~(size_t)255;
    return p;
  };
  __bf16* casb = (__bf16*)alloc((size_t)CC * CC * 2);        // 1.18 MB
  __bf16* w1f  = (__bf16*)alloc((size_t)8 * 36 * 64 * 8 * 2);
  __bf16* w2f  = (__bf16*)alloc((size_t)8 * 72 * 64 * 8 * 2);
  __bf16* xb   = (__bf16*)alloc((size_t)NTOT * 2);           // 50.3 MB
  __bf16* vv   = (__bf16*)alloc((size_t)NTOT * 2);           // 50.3 MB (Z)

  make_cas<<<2304, 256, 0, stream>>>(casb);
  cvt4<<<24576, 256, 0, stream>>>(x, xb);
  pack_w1<<<576, 256, 0, stream>>>(w1, w1f);
  pack_w2<<<1152, 256, 0, stream>>>(w2, w2f);

  // Z = softshrink-MLP(Xbf16 @ CAS), fused per (row-tile, channel-block-pair)
  fused2<<<1024, 384, 0, stream>>>(xb, casb, w1f, w2f, b1, b2, vv);
  // OUT = Z @ CAS / n_tot + X  (counted-vmcnt pipeline + coalesced epilogue)
  gemm_back<<<1536, 256, 0, stream>>>(vv, casb, out, x, 1.0f / 25165824.0f);
}

// Round 4
// 340.891 us; speedup vs baseline: 1.3210x; 1.0809x over previous
//
#include <hip/hip_runtime.h>
#include <hip/hip_bf16.h>
#include <cstdint>
#include <cstddef>

typedef __bf16 bf8_t __attribute__((ext_vector_type(8)));
typedef __bf16 bf4_t __attribute__((ext_vector_type(4)));
typedef float  f4_t  __attribute__((ext_vector_type(4)));

#define CC 768
#define NROWS 32768           // 8*4096
#define NTOT 25165824         // 32768*768

__device__ __forceinline__ void gld16(const void* g, void* l) {
  __builtin_amdgcn_global_load_lds(
      (const __attribute__((address_space(1))) void*)g,
      (__attribute__((address_space(3))) void*)l, 16, 0, 0);
}

// ---------------- prep kernels ----------------

__global__ void make_cas(__bf16* __restrict__ cas) {
  int idx = blockIdx.x * 256 + threadIdx.x;      // 589824 total
  int i = idx / CC, j = idx - i * CC;
  int ij = (i * j) % CC;                          // exact arg reduction
  float ang = 6.283185307179586f * (float)ij / (float)CC;
  cas[idx] = (__bf16)(__cosf(ang) + __sinf(ang));
}

__global__ void cvt4(const float* __restrict__ x, __bf16* __restrict__ o) {
  int i = (blockIdx.x * 256 + threadIdx.x) * 4;
  float4 v = *(const float4*)(x + i);
  bf4_t r;
  r[0] = (__bf16)v.x; r[1] = (__bf16)v.y; r[2] = (__bf16)v.z; r[3] = (__bf16)v.w;
  *(bf4_t*)(o + i) = r;
}

// pack weights into MFMA B-fragment order: frag[(kt*12+nt)*64 + lane][j]
// B-frag semantics: lane holds B[k = kt*32 + (lane>>4)*8 + j][n = nt*16 + (lane&15)]
__global__ void pack_w1(const float* __restrict__ w1, __bf16* __restrict__ w1f) {
  int f = blockIdx.x * 256 + threadIdx.x;        // < 8*36*64*8 = 147456
  int j = f & 7, lane = (f >> 3) & 63, rest = f >> 9;
  int nt = rest % 12, kt = (rest / 12) % 3, blk = rest / 36;
  int k = kt * 32 + (lane >> 4) * 8 + j;          // 0..95  (input)
  int o = nt * 16 + (lane & 15);                  // 0..191 (output: [real|imag])
  float v = (o < 96) ? w1[(0 * 8 + blk) * 9216 + k * 96 + o]
                     : w1[(1 * 8 + blk) * 9216 + k * 96 + (o - 96)];
  w1f[f] = (__bf16)v;
}

__global__ void pack_w2(const float* __restrict__ w2, __bf16* __restrict__ w2f) {
  int f = blockIdx.x * 256 + threadIdx.x;        // < 8*72*64*8 = 294912
  int j = f & 7, lane = (f >> 3) & 63, rest = f >> 9;
  int nt = rest % 12, kt = (rest / 12) % 6, blk = rest / 72;
  int i = kt * 32 + (lane >> 4) * 8 + j;          // 0..191 (hidden: [ar|ai])
  int o = nt * 16 + (lane & 15);                  // 0..191 (out: [yr|yi])
  float v;
  if (o < 96) v = (i < 96) ?  w2[(0 * 8 + blk) * 9216 + i * 96 + o]
                           : -w2[(1 * 8 + blk) * 9216 + (i - 96) * 96 + o];
  else        v = (i < 96) ?  w2[(1 * 8 + blk) * 9216 + i * 96 + (o - 96)]
                           :  w2[(0 * 8 + blk) * 9216 + (i - 96) * 96 + (o - 96)];
  w2f[f] = (__bf16)v;
}

// ---------------- back GEMM v2 (validated round 3: ~58 us) ----------------------------
// counted-vmcnt 3-buffer pipeline + LDS-staged coalesced epilogue
__global__ __launch_bounds__(256, 2) void gemm_back(
    const __bf16* __restrict__ Zb, const __bf16* __restrict__ BT,
    float* __restrict__ Cf, const float* __restrict__ Xres, float scale)
{
  __shared__ __align__(16) char smem[49152];     // 3 x (sA 8KB | sB 8KB)
  const int t = threadIdx.x;
  const int lane = t & 63, wid = t >> 6;
  const int wm = (wid >> 1) * 64, wn = (wid & 1) * 64;

  const int id = blockIdx.x;
  const int sid = (id & 7) * 192 + (id >> 3);
  const int m0 = (sid / 6) * 128, n0 = (sid % 6) * 128;

  const int q = lane >> 4, r = lane & 15;
  const __bf16* gA = Zb + (size_t)(m0 + (t >> 2)) * CC + (t & 3) * 8;
  const __bf16* gB = BT + (size_t)(n0 + (t >> 2)) * CC + (t & 3) * 8;
  const int ldsOff = (t >> 2) * 32 + (t & 3) * 8;  // byte off = t*16 (lane-linear)

  auto stage = [&](int b, int tile) {
    int k0 = tile * 32;
    __bf16* lA = (__bf16*)(smem + b * 16384) + ldsOff;
    __bf16* lB = (__bf16*)(smem + b * 16384 + 8192) + ldsOff;
    gld16(gA + k0, lA);
    gld16(gA + (size_t)64 * CC + k0, lA + 64 * 32);
    gld16(gB + k0, lB);
    gld16(gB + (size_t)64 * CC + k0, lB + 64 * 32);
  };

  f4_t acc[4][4] = {};
  stage(0, 0);
  stage(1, 1);
  for (int tile = 0; tile < 24; ++tile) {
    int nt = tile + 2; if (nt > 23) nt = 23;       // clamped duplicate in tail
    stage((tile + 2) % 3, nt);
    asm volatile("s_waitcnt vmcnt(8)" ::: "memory");   // tile `tile` complete
    __builtin_amdgcn_s_barrier();
    const __bf16* sA = (const __bf16*)(smem + (tile % 3) * 16384);
    const __bf16* sB = sA + 8192 / 2;
    bf8_t af[4], bfr[4];
#pragma unroll
    for (int i = 0; i < 4; i++)
      af[i] = *(const bf8_t*)(sA + (wm + i * 16 + r) * 32 + q * 8);
#pragma unroll
    for (int j = 0; j < 4; j++)
      bfr[j] = *(const bf8_t*)(sB + (wn + j * 16 + r) * 32 + q * 8);
#pragma unroll
    for (int i = 0; i < 4; i++)
#pragma unroll
      for (int j = 0; j < 4; j++)
        acc[i][j] = __builtin_amdgcn_mfma_f32_16x16x32_bf16(af[i], bfr[j], acc[i][j], 0, 0, 0);
    __builtin_amdgcn_s_barrier();   // all waves done with buf[tile%3] before restage
  }

  // ---- epilogue: LDS-staged coalesced f32 writeback, two 64-row halves ----
  float* cs = (float*)smem;                        // 64 x 132 f32 = 33 KB < 48 KB
#pragma unroll
  for (int h = 0; h < 2; ++h) {
    __builtin_amdgcn_s_barrier();                  // prev half's copy-out done
    if ((wid >> 1) == h) {
#pragma unroll
      for (int i = 0; i < 4; i++)
#pragma unroll
        for (int j = 0; j < 4; j++)
#pragma unroll
          for (int rr = 0; rr < 4; rr++)
            cs[(i * 16 + q * 4 + rr) * 132 + wn + j * 16 + r] = acc[i][j][rr];
    }
    __builtin_amdgcn_s_barrier();
    const int u = t & 31, row8 = t >> 5;
#pragma unroll
    for (int p = 0; p < 8; ++p) {
      int rl = p * 8 + row8;
      size_t goff = (size_t)(m0 + h * 64 + rl) * CC + n0 + u * 4;
      f4_t xr = *(const f4_t*)(Xres + goff);
      f4_t cv = *(const f4_t*)(cs + rl * 132 + u * 4);
      f4_t o;
      o[0] = cv[0] * scale + xr[0];
      o[1] = cv[1] * scale + xr[1];
      o[2] = cv[2] * scale + xr[2];
      o[3] = cv[3] * scale + xr[3];
      *(f4_t*)(Cf + goff) = o;
    }
  }
}

// ---------------- fused3: counted-vmcnt pipelined V-GEMM + 2x block-diag MLP ------------
// Round-4 change (isolated): the K-loop adopts gemm_back's proven 3-buffer counted-vmcnt
// pipeline (stage tile t+2 before computing tile t; waves 0-1 issue 4 loads/stage ->
// vmcnt(8), waves 2-5 issue 3 -> vmcnt(6); never drain to 0 in the loop). LDS re-planned:
// staging = 3 x 20 KB at [0,61440); MLP regions alias it (time-disjoint, guarded by one
// vmcnt(0)+barrier drain after the K-loop): Hs [0,25600), vt [25600,51200),
// zl [51200,63488). MLP phases / weights-in-registers / coalesced copy-out unchanged.
__global__ __launch_bounds__(384, 3) void fused3(
    const __bf16* __restrict__ A, const __bf16* __restrict__ BT,
    const __bf16* __restrict__ w1f, const __bf16* __restrict__ w2f,
    const float* __restrict__ b1, const float* __restrict__ b2,
    __bf16* __restrict__ Z)
{
  __shared__ __align__(16) char smem[63488];
  __bf16* Hs = (__bf16*)smem;
  __bf16* vt = (__bf16*)(smem + 25600);
  __bf16* zl = (__bf16*)(smem + 51200);

  const int t = threadIdx.x, lane = t & 63, w = t >> 6;   // w in 0..5
  const int id = blockIdx.x;
  const int sid = (id & 7) * 128 + (id >> 3);             // bijective XCD swizzle
  const int cbp = sid & 3;                 // channel-block pair 0..3
  const int m0 = (sid >> 2) * 128;         // row tile
  const int n0 = cbp * 192;
  const int q = lane >> 4, r = lane & 15;

  // ---- K-loop: V[128x192] = A[m0:m0+128,:] @ CAS[:, n0:n0+192], 3-buffer pipeline ----
  const __bf16* gA  = A  + (size_t)(m0 + (t >> 2)) * CC + (t & 3) * 8;
  const __bf16* gA2 = A  + (size_t)(m0 + 96 + (t >> 2)) * CC + (t & 3) * 8;   // t<128
  const __bf16* gB  = BT + (size_t)(n0 + (t >> 2)) * CC + (t & 3) * 8;
  const __bf16* gB2 = BT + (size_t)(n0 + 96 + (t >> 2)) * CC + (t & 3) * 8;

  auto stage = [&](int b, int tile) {
    int k0 = tile * 32;
    char* base = smem + b * 20480;                 // A [0,8192) | B [8192,20480)
    gld16(gA + k0, (__bf16*)base + t * 8);
    if (t < 128) gld16(gA2 + k0, (__bf16*)base + (384 + t) * 8);   // waves 0,1
    gld16(gB + k0, (__bf16*)(base + 8192) + t * 8);
    gld16(gB2 + k0, (__bf16*)(base + 8192) + (384 + t) * 8);
  };

  f4_t acc[8][2] = {};
  stage(0, 0);
  stage(1, 1);
  for (int tile = 0; tile < 24; ++tile) {
    int nt = tile + 2; if (nt > 23) nt = 23;       // clamped duplicate in tail
    stage((tile + 2) % 3, nt);
    // tile's stage complete when 2 newer stages remain in flight:
    if (w < 2) asm volatile("s_waitcnt vmcnt(8)" ::: "memory");   // 4 loads/stage
    else       asm volatile("s_waitcnt vmcnt(6)" ::: "memory");   // 3 loads/stage
    __builtin_amdgcn_s_barrier();
    const __bf16* sA = (const __bf16*)(smem + (tile % 3) * 20480);
    const __bf16* sB = (const __bf16*)(smem + (tile % 3) * 20480 + 8192);
    bf8_t af[8], bfr[2];
#pragma unroll
    for (int i = 0; i < 8; i++)
      af[i] = *(const bf8_t*)(sA + (i * 16 + r) * 32 + q * 8);
#pragma unroll
    for (int j = 0; j < 2; j++)
      bfr[j] = *(const bf8_t*)(sB + (w * 32 + j * 16 + r) * 32 + q * 8);
#pragma unroll
    for (int i = 0; i < 8; i++)
#pragma unroll
      for (int j = 0; j < 2; j++)
        acc[i][j] = __builtin_amdgcn_mfma_f32_16x16x32_bf16(af[i], bfr[j], acc[i][j], 0, 0, 0);
    __builtin_amdgcn_s_barrier();   // all waves done with buf[tile%3] before restage
  }
  // drain duplicate tail stages before the MLP regions (which alias staging buffers)
  asm volatile("s_waitcnt vmcnt(0)" ::: "memory");
  __builtin_amdgcn_s_barrier();

  // ---- two 64-row half-passes (unchanged MLP body) ----
#pragma unroll
  for (int h = 0; h < 2; h++) {
#pragma unroll
    for (int ii = 0; ii < 4; ii++)
#pragma unroll
      for (int j = 0; j < 2; j++) {
        int col = w * 32 + j * 16 + r;
#pragma unroll
        for (int rr = 0; rr < 4; rr++) {
          int row = ii * 16 + q * 4 + rr;
          vt[row * 200 + col] = (__bf16)acc[h * 4 + ii][j][rr];
        }
      }
    __syncthreads();

#pragma unroll
    for (int cb = 0; cb < 2; cb++) {
      const int bidx = cbp * 2 + cb;
      const __bf16* w1b = w1f + (size_t)bidx * (36 * 64 * 8);
      const __bf16* w2b = w2f + (size_t)bidx * (72 * 64 * 8);
      bf8_t w1r[3][2], w2r[6][2];
#pragma unroll
      for (int kt = 0; kt < 3; kt++)
#pragma unroll
        for (int j = 0; j < 2; j++)
          w1r[kt][j] = *(const bf8_t*)(w1b + ((size_t)(kt * 12 + 2 * w + j) * 64 + lane) * 8);
#pragma unroll
      for (int kt = 0; kt < 6; kt++) {
        w2r[kt][0] = *(const bf8_t*)(w2b + ((size_t)(kt * 12 + w) * 64 + lane) * 8);
        w2r[kt][1] = *(const bf8_t*)(w2b + ((size_t)(kt * 12 + w + 6) * 64 + lane) * 8);
      }
      float bb[2];
#pragma unroll
      for (int j = 0; j < 2; j++) {
        int c = (2 * w + j) * 16 + r;
        bb[j] = (c < 96) ? b1[bidx * 96 + c] : b1[768 + bidx * 96 + (c - 96)];
      }
      const float br = b2[bidx * 96 + w * 16 + r];
      const float bi = b2[768 + bidx * 96 + w * 16 + r];

      // phase 1: Hs[64][192] = relu(V[:,cb*96:+96] W1 + b1), wave w: cols [32w,32w+32)
#pragma unroll
      for (int rt = 0; rt < 4; rt++) {
        const __bf16* vp = vt + (rt * 16 + r) * 200 + cb * 96 + q * 8;
        f4_t a0 = {}, a1 = {};
#pragma unroll
        for (int kt = 0; kt < 3; kt++) {
          bf8_t a = *(const bf8_t*)(vp + kt * 32);
          a0 = __builtin_amdgcn_mfma_f32_16x16x32_bf16(a, w1r[kt][0], a0, 0, 0, 0);
          a1 = __builtin_amdgcn_mfma_f32_16x16x32_bf16(a, w1r[kt][1], a1, 0, 0, 0);
        }
#pragma unroll
        for (int j = 0; j < 2; j++) {
          int c = (2 * w + j) * 16 + r;
          f4_t* ap = j ? &a1 : &a0;
#pragma unroll
          for (int rr = 0; rr < 4; rr++) {
            float v = (*ap)[rr] + bb[j];
            Hs[(rt * 16 + q * 4 + rr) * 200 + c] = (__bf16)(v > 0.f ? v : 0.f);
          }
        }
      }
      __syncthreads();
      // phase 2: y = H W2pack + b2; z = ss(yr)-ss(yi); wave w -> z cols [16w,16w+16)
#pragma unroll
      for (int rt = 0; rt < 4; rt++) {
        f4_t ar = {}, ai = {};
#pragma unroll
        for (int kt = 0; kt < 6; kt++) {
          bf8_t a = *(const bf8_t*)(&Hs[(rt * 16 + r) * 200 + kt * 32 + q * 8]);
          ar = __builtin_amdgcn_mfma_f32_16x16x32_bf16(a, w2r[kt][0], ar, 0, 0, 0);
          ai = __builtin_amdgcn_mfma_f32_16x16x32_bf16(a, w2r[kt][1], ai, 0, 0, 0);
        }
#pragma unroll
        for (int rr = 0; rr < 4; rr++) {
          float yr = ar[rr] + br, yi = ai[rr] + bi;
          float sr = fabsf(yr) - 0.01f; sr = sr > 0.f ? copysignf(sr, yr) : 0.f;
          float si = fabsf(yi) - 0.01f; si = si > 0.f ? copysignf(si, yi) : 0.f;
          zl[(rt * 16 + q * 4 + rr) * 96 + w * 16 + r] = (__bf16)(sr - si);
        }
      }
      __syncthreads();
      // copy-out: 64 rows x 48 dwords, coalesced
      {
        const uint32_t* zsrc = (const uint32_t*)zl;
        int cdw = t % 48, crow = t / 48;
        int rbase = m0 + h * 64;
#pragma unroll
        for (int it = 0; it < 8; it++) {
          int row = it * 8 + crow;
          uint32_t* dst = (uint32_t*)(Z + (size_t)(rbase + row) * CC + n0 + cb * 96);
          dst[cdw] = zsrc[row * 48 + cdw];
        }
      }
    }
  }
}

// ---------------- launch ----------------

extern "C" void kernel_launch(void* const* d_in, const int* in_sizes, int n_in,
                              void* d_out, int out_size, void* d_ws, size_t ws_size,
                              hipStream_t stream) {
  const float* x  = (const float*)d_in[0];
  const float* w1 = (const float*)d_in[1];
  const float* b1 = (const float*)d_in[2];
  const float* w2 = (const float*)d_in[3];
  const float* b2 = (const float*)d_in[4];
  float* out = (float*)d_out;

  char* ws = (char*)d_ws;
  size_t off = 0;
  auto alloc = [&](size_t bytes) {
    char* p = ws + off;
    off += (bytes + 255) & ~(size_t)255;
    return p;
  };
  __bf16* casb = (__bf16*)alloc((size_t)CC * CC * 2);        // 1.18 MB
  __bf16* w1f  = (__bf16*)alloc((size_t)8 * 36 * 64 * 8 * 2);
  __bf16* w2f  = (__bf16*)alloc((size_t)8 * 72 * 64 * 8 * 2);
  __bf16* xb   = (__bf16*)alloc((size_t)NTOT * 2);           // 50.3 MB
  __bf16* vv   = (__bf16*)alloc((size_t)NTOT * 2);           // 50.3 MB (Z)

  make_cas<<<2304, 256, 0, stream>>>(casb);
  cvt4<<<24576, 256, 0, stream>>>(x, xb);
  pack_w1<<<576, 256, 0, stream>>>(w1, w1f);
  pack_w2<<<1152, 256, 0, stream>>>(w2, w2f);

  // Z = softshrink-MLP(Xbf16 @ CAS), fused per (row-tile, channel-block-pair)
  fused3<<<1024, 384, 0, stream>>>(xb, casb, w1f, w2f, b1, b2, vv);
  // OUT = Z @ CAS / n_tot + X  (counted-vmcnt pipeline + coalesced epilogue)
  gemm_back<<<1536, 256, 0, stream>>>(vv, casb, out, x, 1.0f / 25165824.0f);
}